// Round 8
// baseline (431.958 us; speedup 1.0000x reference)
//
#include <hip/hip_runtime.h>
#include <math.h>

#define C_DIM 512
#define T_DIM 2048
#define B_DIM 8

typedef _Float16 f16;
typedef __attribute__((ext_vector_type(8))) _Float16 half8;
typedef __attribute__((ext_vector_type(4))) _Float16 half4;
typedef __attribute__((ext_vector_type(4))) float floatx4;

// ---------------------------------------------------------------------------
// prep: z<8 -> transpose x[b=z] [C][T] fp32 -> xt [T][C] fp16 (32x32 tiles);
//       z==8 -> convert 4 weight matrices to fp16 (+ concat theta/phi bias).
// ---------------------------------------------------------------------------
__global__ __launch_bounds__(256) void prep_kernel(
    const float* __restrict__ x, f16* __restrict__ xt,
    const float* __restrict__ w0, const float* __restrict__ w1,
    const float* __restrict__ w2, const float* __restrict__ w3,
    f16* __restrict__ o0, f16* __restrict__ o1,
    f16* __restrict__ o2, f16* __restrict__ o3,
    const float* __restrict__ b0, const float* __restrict__ b1,
    float* __restrict__ btp)
{
    const int tid = threadIdx.x;
    if (blockIdx.z == 8) {
        const int idx = blockIdx.y * 64 + blockIdx.x;    // 0..1023
        const int wsel = idx >> 8, blk = idx & 255;
        const float* src; f16* dst;
        switch (wsel) {
            case 0:  src = w0; dst = o0; break;
            case 1:  src = w1; dst = o1; break;
            case 2:  src = w2; dst = o2; break;
            default: src = w3; dst = o3; break;
        }
        const int e = blk * 1024 + tid * 4;
        const float4 v = *(const float4*)(src + e);
        half4 h; h[0] = (f16)v.x; h[1] = (f16)v.y; h[2] = (f16)v.z; h[3] = (f16)v.w;
        *(half4*)(dst + e) = h;
        if (idx == 0) {
            const int i = tid * 4;
            const float4 bv = (i < 512) ? *(const float4*)(b0 + i)
                                        : *(const float4*)(b1 + i - 512);
            *(float4*)(btp + i) = bv;
        }
        return;
    }
    __shared__ float xs[32][33];
    const int b  = blockIdx.z;
    const int t0 = blockIdx.x * 32, c0 = blockIdx.y * 32;
    const float* xb = x + (size_t)b * C_DIM * T_DIM;
    const int r = tid >> 3, q = tid & 7;

    const float4 v = *(const float4*)(xb + (size_t)(c0 + r) * T_DIM + t0 + q * 4);
    xs[r][q * 4 + 0] = v.x; xs[r][q * 4 + 1] = v.y;
    xs[r][q * 4 + 2] = v.z; xs[r][q * 4 + 3] = v.w;
    __syncthreads();

    f16* xtb = xt + (size_t)b * C_DIM * T_DIM;
    half4 h;
    h[0] = (f16)xs[q * 4 + 0][r]; h[1] = (f16)xs[q * 4 + 1][r];
    h[2] = (f16)xs[q * 4 + 2][r]; h[3] = (f16)xs[q * 4 + 3][r];
    *(half4*)(xtb + (size_t)(t0 + r) * C_DIM + c0 + q * 4) = h;
}

// ---------------------------------------------------------------------------
// TN MFMA GEMM: C[i][j] = sum_k A[i][k] * B[j][k]
// Block tile (MI*32) x 128, BK=32. MI=4 -> 128x128 (R6-proven); MI=8 ->
// 256x128: wave tile 128x64 gives 43.7 FLOP per LDS byte (vs 32) and half
// the barriers per FLOP -- attacks the measured LDS-read-BW bound
// (R6: 32 KB LDS reads vs 78 cyc MFMA per iter -> MfmaUtil 26%).
// Named-register distance-2 prefetch (arrays indexed only by unrolled
// constants -- R5's runtime index forced scratch spills). LDS dbuf, XOR slot
// swizzle, XCD-aware tile remap (consecutive IDs round-robin XCDs; each XCD
// gets a contiguous RIxRJ tile rectangle -> R7 cut scores FETCH 148->49 MB).
// MODE: 0 = f16 store; 1 = f16 relu(+bias[col]); 2 = f16 relu(+bias[row]);
// 3 = fp32 relu(+bias[row]) + resid.
// ---------------------------------------------------------------------------
template<int MI, int MODE>
__global__ __launch_bounds__(256, 2) void gemm_tn(
    const f16* __restrict__ A, size_t sA, int lda,
    const f16* __restrict__ B, size_t sB, int ldb,
    void* __restrict__ Cp, size_t sC, int ldc,
    const float* __restrict__ bias,
    const float* __restrict__ resid, size_t sR,
    int K, int RI, int RJ)
{
    constexpr int BM = MI * 32;      // block rows
    constexpr int NA = MI / 2;       // A 16B-chunk loads per thread per tile
    __shared__ __align__(16) f16 As[2][BM * 32];
    __shared__ __align__(16) f16 Bs[2][128 * 32];

    // XCD-aware tile mapping: 8 regions of RI x RJ tiles, one per XCD
    const int gx = gridDim.x;
    const int flat = blockIdx.y * gx + blockIdx.x;
    const int region = flat & 7;
    const int idx = flat >> 3;
    const int NRJ = gx / RJ;
    const int rI = region / NRJ, rJ = region % NRJ;
    const int ii = idx / RJ, jj = idx % RJ;
    const int i0 = (rI * RI + ii) * BM;
    const int j0 = (rJ * RJ + jj) * 128;

    const int bz = blockIdx.z;
    A += (size_t)bz * sA;
    B += (size_t)bz * sB;

    const int tid  = threadIdx.x;
    const int lane = tid & 63;
    const int wave = tid >> 6;
    const int wy = wave >> 1, wx = wave & 1;
    const int quad = lane >> 4, l16 = lane & 15;

    // staging map: A tile = BM rows x 4 chunks of 16B, thread covers rows
    // rowA + u*64; B tile = 128 rows x 4 chunks, rows rowA, rowA+64.
    const int rowA = tid >> 2, ch = tid & 3;
    const int slot = (ch ^ (rowA & 3)) << 3;   // (row+64k)&3 == rowA&3
    int wA[NA]; const f16* gA[NA];
    #pragma unroll
    for (int u = 0; u < NA; ++u) {
        const int r = rowA + u * 64;
        wA[u] = r * 32 + slot;
        gA[u] = A + (size_t)(i0 + r) * lda + ch * 8;
    }
    const int wB1 = rowA * 32 + slot, wB2 = (rowA + 64) * 32 + slot;
    const f16* gB1 = B + (size_t)(j0 + rowA) * ldb + ch * 8;
    const f16* gB2 = B + (size_t)(j0 + rowA + 64) * ldb + ch * 8;

    // frag-read slot: quad ^ (row&3); row&3 == l16&3 for all frag rows
    const int xa = (quad ^ (l16 & 3)) << 3;

    const int nt = K >> 5;   // even for all our shapes

    // prologue: tile 0 -> set0, tile 1 -> set1
    float4 a0[NA], a1[NA], b0a, b0b, b1a, b1b;
    #pragma unroll
    for (int u = 0; u < NA; ++u) {
        a0[u] = *(const float4*)(gA[u]);
        a1[u] = *(const float4*)(gA[u] + 32);
    }
    b0a = *(const float4*)(gB1);      b0b = *(const float4*)(gB2);
    b1a = *(const float4*)(gB1 + 32); b1b = *(const float4*)(gB2 + 32);

    floatx4 acc[MI][4] = {};

    for (int t = 0; t < nt; t += 2) {
        // ---- even iter: buffer 0, set 0 ----
        #pragma unroll
        for (int u = 0; u < NA; ++u) *(float4*)&As[0][wA[u]] = a0[u];
        *(float4*)&Bs[0][wB1] = b0a;
        *(float4*)&Bs[0][wB2] = b0b;
        if (t + 2 < nt) {
            const int off = (t + 2) * 32;
            #pragma unroll
            for (int u = 0; u < NA; ++u) a0[u] = *(const float4*)(gA[u] + off);
            b0a = *(const float4*)(gB1 + off);
            b0b = *(const float4*)(gB2 + off);
        }
        __syncthreads();
        {
            half8 af[MI], bf[4];
            #pragma unroll
            for (int mi = 0; mi < MI; ++mi)
                af[mi] = *(const half8*)&As[0][(wy * (MI * 16) + mi * 16 + l16) * 32 + xa];
            #pragma unroll
            for (int ni = 0; ni < 4; ++ni)
                bf[ni] = *(const half8*)&Bs[0][(wx * 64 + ni * 16 + l16) * 32 + xa];
            #pragma unroll
            for (int mi = 0; mi < MI; ++mi)
                #pragma unroll
                for (int ni = 0; ni < 4; ++ni)
                    acc[mi][ni] = __builtin_amdgcn_mfma_f32_16x16x32_f16(
                        af[mi], bf[ni], acc[mi][ni], 0, 0, 0);
        }
        // ---- odd iter: buffer 1, set 1 ----
        #pragma unroll
        for (int u = 0; u < NA; ++u) *(float4*)&As[1][wA[u]] = a1[u];
        *(float4*)&Bs[1][wB1] = b1a;
        *(float4*)&Bs[1][wB2] = b1b;
        if (t + 3 < nt) {
            const int off = (t + 3) * 32;
            #pragma unroll
            for (int u = 0; u < NA; ++u) a1[u] = *(const float4*)(gA[u] + off);
            b1a = *(const float4*)(gB1 + off);
            b1b = *(const float4*)(gB2 + off);
        }
        __syncthreads();
        {
            half8 af[MI], bf[4];
            #pragma unroll
            for (int mi = 0; mi < MI; ++mi)
                af[mi] = *(const half8*)&As[1][(wy * (MI * 16) + mi * 16 + l16) * 32 + xa];
            #pragma unroll
            for (int ni = 0; ni < 4; ++ni)
                bf[ni] = *(const half8*)&Bs[1][(wx * 64 + ni * 16 + l16) * 32 + xa];
            #pragma unroll
            for (int mi = 0; mi < MI; ++mi)
                #pragma unroll
                for (int ni = 0; ni < 4; ++ni)
                    acc[mi][ni] = __builtin_amdgcn_mfma_f32_16x16x32_f16(
                        af[mi], bf[ni], acc[mi][ni], 0, 0, 0);
        }
    }

    // epilogue: C/D layout col = lane&15, row = quad*4 + reg (m89-verified)
    #pragma unroll
    for (int mi = 0; mi < MI; ++mi) {
        #pragma unroll
        for (int ni = 0; ni < 4; ++ni) {
            const int col = j0 + wx * 64 + ni * 16 + l16;
            #pragma unroll
            for (int r = 0; r < 4; ++r) {
                const int row = i0 + wy * (MI * 16) + mi * 16 + quad * 4 + r;
                float v = acc[mi][ni][r];
                if (MODE == 1) { v += bias[col]; v = v > 0.f ? v : 0.f; }
                if (MODE == 2) { v += bias[row]; v = v > 0.f ? v : 0.f; }
                if (MODE == 3) {
                    v += bias[row];
                    v = v > 0.f ? v : 0.f;
                    v += resid[(size_t)bz * sR + (size_t)row * ldc + col];
                    ((float*)Cp)[(size_t)bz * sC + (size_t)row * ldc + col] = v;
                } else {
                    ((f16*)Cp)[(size_t)bz * sC + (size_t)row * ldc + col] = (f16)v;
                }
            }
        }
    }
}

// ---------------------------------------------------------------------------
// in-place fp16 softmax over rows of 2048 (fp32 math)
// ---------------------------------------------------------------------------
__global__ __launch_bounds__(256) void softmax_f16_kernel(f16* __restrict__ S)
{
    f16* p = S + (size_t)blockIdx.x * T_DIM;
    const int tid = threadIdx.x;

    half8 hv = *((const half8*)p + tid);
    float v[8];
    float lmax = -1e30f;
    #pragma unroll
    for (int c = 0; c < 8; ++c) { v[c] = (float)hv[c]; lmax = fmaxf(lmax, v[c]); }
    #pragma unroll
    for (int off = 32; off; off >>= 1)
        lmax = fmaxf(lmax, __shfl_down(lmax, off));
    __shared__ float redm[4];
    if ((tid & 63) == 0) redm[tid >> 6] = lmax;
    __syncthreads();
    const float m = fmaxf(fmaxf(redm[0], redm[1]), fmaxf(redm[2], redm[3]));

    float lsum = 0.f;
    #pragma unroll
    for (int c = 0; c < 8; ++c) { v[c] = __expf(v[c] - m); lsum += v[c]; }
    #pragma unroll
    for (int off = 32; off; off >>= 1)
        lsum += __shfl_down(lsum, off);
    __shared__ float reds[4];
    if ((tid & 63) == 0) reds[tid >> 6] = lsum;
    __syncthreads();
    const float inv = 1.f / (reds[0] + reds[1] + reds[2] + reds[3]);

    #pragma unroll
    for (int c = 0; c < 8; ++c) hv[c] = (f16)(v[c] * inv);
    *((half8*)p + tid) = hv;
}

// ---------------------------------------------------------------------------
extern "C" void kernel_launch(void* const* d_in, const int* in_sizes, int n_in,
                              void* d_out, int out_size, void* d_ws, size_t ws_size,
                              hipStream_t stream)
{
    const float* x       = (const float*)d_in[0];
    const float* w_theta = (const float*)d_in[1];
    const float* b_theta = (const float*)d_in[2];
    const float* w_phi   = (const float*)d_in[3];
    const float* b_phi   = (const float*)d_in[4];
    const float* w_g     = (const float*)d_in[5];
    const float* b_g     = (const float*)d_in[6];
    const float* w_w     = (const float*)d_in[7];
    const float* b_w     = (const float*)d_in[8];
    float* out = (float*)d_out;

    const size_t FE = (size_t)B_DIM * C_DIM * T_DIM;   // 8.4M
    const size_t TC = (size_t)T_DIM * C_DIM;
    const size_t TT = (size_t)T_DIM * T_DIM;

    f16* xt      = (f16*)d_ws;
    f16* wtp     = xt + FE;              // merged theta|phi weights [1024][512]
    f16* wg_h    = wtp + 524288;
    f16* ww_h    = wg_h + 262144;
    float* btp   = (float*)(ww_h + 262144);   // merged bias [1024] fp32
    f16* tp      = (f16*)(btp + 1024);   // theta|phi acts [B][T][1024]
    f16* g       = tp + (size_t)B_DIM * T_DIM * 1024;
    f16* scores  = g + FE;               // B*T*T f16 = 67 MB
    f16* feature = tp;                   // tp dead after scores GEMM

    const dim3 blk(256);

    prep_kernel<<<dim3(64, 16, 9), blk, 0, stream>>>(
        x, xt, w_theta, w_phi, w_g, w_w,
        wtp, wtp + 262144, wg_h, ww_h, b_theta, b_phi, btp);

    // merged theta|phi conv: tp[t][0:1024] = relu(xt . wtp + btp)  M=T,N=1024
    gemm_tn<8, 1><<<dim3(8, 8, B_DIM), blk, 0, stream>>>(
        xt, TC, C_DIM, wtp, 0, C_DIM, tp, (size_t)T_DIM * 1024, 1024,
        btp, nullptr, 0, C_DIM, 2, 4);
    // g[c][t] = relu(w_g . xt + b_g[c])   M=C, N=T
    gemm_tn<4, 2><<<dim3(16, 4, B_DIM), blk, 0, stream>>>(
        wg_h, 0, C_DIM, xt, TC, C_DIM, g, TC, T_DIM,
        b_g, nullptr, 0, C_DIM, 1, 8);
    // scores[i][j] = theta . phi   M=T(256-tiles), N=T
    gemm_tn<8, 0><<<dim3(16, 8, B_DIM), blk, 0, stream>>>(
        tp, (size_t)T_DIM * 1024, 1024, tp + 512, (size_t)T_DIM * 1024, 1024,
        scores, TT, T_DIM, nullptr, nullptr, 0, C_DIM, 2, 8);
    softmax_f16_kernel<<<dim3(B_DIM * T_DIM), blk, 0, stream>>>(scores);
    // feature[i][c] = attn . g   M=T, N=C, K=T
    gemm_tn<4, 0><<<dim3(4, 16, B_DIM), blk, 0, stream>>>(
        scores, TT, T_DIM, g, TC, T_DIM, feature, TC, C_DIM,
        nullptr, nullptr, 0, T_DIM, 4, 2);
    // out[c][t] = relu(w_w . feature + b_w[c]) + x   M=C, N=T
    gemm_tn<4, 3><<<dim3(16, 4, B_DIM), blk, 0, stream>>>(
        ww_h, 0, C_DIM, feature, TC, C_DIM, out, TC, T_DIM,
        b_w, x, TC, C_DIM, 1, 8);
}